// Round 19
// baseline (69.357 us; speedup 1.0000x reference)
//
#include <hip/hip_runtime.h>
#include <hip/hip_bf16.h>
#include <math.h>

#define NN   4096
#define KNB  10
#define ED   128
#define EFD  64
#define TD   64
#define DD   192     // E + T
#define KEYD 256     // E + EF + T
#define KDD  2560    // KEYD * KNB
#define HD   96      // DD / H
#define NH   2
#define NSPLIT 4     // key-splits for attention (opart splits)
#define KVSPLIT 2    // K-splits for kv gemm

typedef __attribute__((ext_vector_type(8))) short bf16x8;
typedef __attribute__((ext_vector_type(4))) float f32x4;
typedef __attribute__((ext_vector_type(2))) unsigned int u32x2;

__device__ inline short f2bf(float f) {
    union { float f; unsigned int u; } c; c.f = f;
    unsigned int r = (c.u + 0x7FFFu + ((c.u >> 16) & 1u)) >> 16;
    return (short)r;
}

__device__ inline float bf2f(short s) {
    union { unsigned int u; float f; } c;
    c.u = ((unsigned int)(unsigned short)s) << 16;
    return c.f;
}

__device__ inline void gload_lds16(const void* g, void* lds) {
    __builtin_amdgcn_global_load_lds(
        (const __attribute__((address_space(1))) void*)g,
        (__attribute__((address_space(3))) void*)lds, 16, 0, 0);
}

// ---------------- merged prep: transposes + MLP fold + bf16 conversions ----------------
__global__ __launch_bounds__(256) void prep_convert(
    const float* __restrict__ Wk, const float* __restrict__ Wv,
    const float* __restrict__ Wq,
    const float* __restrict__ Wo, const float* __restrict__ bo,
    const float* __restrict__ W1, const float* __restrict__ b1,
    const float* __restrict__ W2,
    const float* __restrict__ features, const float* __restrict__ edge_feats,
    const float* __restrict__ time_feats, const int* __restrict__ node_idx,
    short* __restrict__ WkT, short* __restrict__ WvT, short* __restrict__ WqT,
    short* __restrict__ WcatT, short* __restrict__ W2T, float* __restrict__ bfold,
    short* __restrict__ featbf, short* __restrict__ xb,
    short* __restrict__ edgebf, short* __restrict__ timebf)
{
    int blk = blockIdx.x, t = threadIdx.x;
    if (blk < 254) {
        __shared__ float ts[64][65];
        const float* W; short* WT; int src_ld, dst_ld, k0, n0;
        if (blk < 240) {            // Wk / Wv : [2560][192] -> [192][2560]
            int z = blk / 120, r = blk % 120;
            W = z ? Wv : Wk; WT = z ? WvT : WkT;
            src_ld = DD; dst_ld = KDD; k0 = (r % 40) * 64; n0 = (r / 40) * 64;
        } else if (blk < 246) {     // Wq : [128][192] -> [192][128]
            int r = blk - 240;
            W = Wq; WT = WqT; src_ld = DD; dst_ld = ED;
            k0 = (r % 2) * 64; n0 = (r / 2) * 64;
        } else if (blk < 250) {     // W1 rows 0..127 -> WcatT[:, 0:128] (ld 320)
            int r = blk - 246;
            W = W1; WT = WcatT; src_ld = ED; dst_ld = 320;
            k0 = (r % 2) * 64; n0 = (r / 2) * 64;
        } else {                    // W2 : [128][128] -> W2T
            int r = blk - 250;
            W = W2; WT = W2T; src_ld = ED; dst_ld = ED;
            k0 = (r % 2) * 64; n0 = (r / 2) * 64;
        }
        #pragma unroll
        for (int j = 0; j < 4; ++j) {
            int k = (t >> 4) + j * 16, n4 = (t & 15) * 4;
            float4 v = *(const float4*)&W[(size_t)(k0 + k) * src_ld + n0 + n4];
            ts[k][n4] = v.x; ts[k][n4 + 1] = v.y; ts[k][n4 + 2] = v.z; ts[k][n4 + 3] = v.w;
        }
        __syncthreads();
        int n = t >> 2, kc = (t & 3) * 16;
        short tmp[16];
        #pragma unroll
        for (int j = 0; j < 16; ++j) tmp[j] = f2bf(ts[kc + j][n]);
        *(bf16x8*)&WT[(size_t)(n0 + n) * dst_ld + k0 + kc] = *(bf16x8*)&tmp[0];
        *(bf16x8*)&WT[(size_t)(n0 + n) * dst_ld + k0 + kc + 8] = *(bf16x8*)&tmp[8];
    } else if (blk == 254) {
        if (t < 128) {
            float s = 0.f;
            for (int j = 0; j < DD; ++j) s += bo[j] * W1[(size_t)(ED + j) * ED + t];
            bfold[t] = s + b1[t];
        }
    } else if (blk < 447) {
        int d = blk - 255;              // 0..191
        if (t < 128) {
            float s = 0.f;
            for (int j = 0; j < DD; ++j)
                s += Wo[(size_t)d * DD + j] * W1[(size_t)(ED + j) * ED + t];
            WcatT[t * 320 + ED + d] = f2bf(s);
        }
    } else {
        int cb = blk - 447;             // 0..6143
        if (cb < 512) {                 // features -> featbf
            int e4 = cb * 256 + t;
            float4 v = *(const float4*)&features[(size_t)e4 * 4];
            short4 o; o.x = f2bf(v.x); o.y = f2bf(v.y); o.z = f2bf(v.z); o.w = f2bf(v.w);
            *(short4*)&featbf[(size_t)e4 * 4] = o;
        } else if (cb < 1024) {         // features[node_idx] -> xb
            int l4 = (cb - 512) * 256 + t;
            int n = l4 >> 5, c = (l4 & 31) * 4;
            float4 v = *(const float4*)&features[(size_t)node_idx[n] * ED + c];
            short4 o; o.x = f2bf(v.x); o.y = f2bf(v.y); o.z = f2bf(v.z); o.w = f2bf(v.w);
            *(short4*)&xb[(size_t)n * ED + c] = o;
        } else if (cb < 3584) {         // edge_feats -> edgebf
            int l4 = (cb - 1024) * 256 + t;
            float4 v = *(const float4*)&edge_feats[(size_t)l4 * 4];
            short4 o; o.x = f2bf(v.x); o.y = f2bf(v.y); o.z = f2bf(v.z); o.w = f2bf(v.w);
            *(short4*)&edgebf[(size_t)l4 * 4] = o;
        } else {                        // time_feats -> timebf
            int l4 = (cb - 3584) * 256 + t;
            float4 v = *(const float4*)&time_feats[(size_t)l4 * 4];
            short4 o; o.x = f2bf(v.x); o.y = f2bf(v.y); o.z = f2bf(v.z); o.w = f2bf(v.w);
            *(short4*)&timebf[(size_t)l4 * 4] = o;
        }
    }
}

// ---------------- K+V paired projection (direct gather, K-split x2) + Q projection ----------
// ids 0..191: kv blocks (each computes BOTH K and V 64-col tiles; 20 K-steps).
// ids 192..383: q blocks.  Grid = 384 <= 512 co-resident capacity: no tail round.
__global__ __launch_bounds__(256) void kvq_gemm_mfma(
    const short* __restrict__ featbf, const short* __restrict__ edgebf,
    const short* __restrict__ timebf, const int* __restrict__ neighbors,
    const short* __restrict__ WkT, const short* __restrict__ WvT,
    short* __restrict__ psumK, short* __restrict__ psumV,
    const short* __restrict__ xb, const short* __restrict__ WqT,
    const float* __restrict__ bq, short* __restrict__ qb)
{
    __shared__ short As[2][128 * 64];        // 32 KB
    __shared__ short Bs[2][2][64 * 64];      // [dbuf][K=0/V=1] 32 KB
    __shared__ unsigned short nbr[128 * KNB];
    int tid = threadIdx.x, wid = tid >> 6, lane = tid & 63;
    int lx = lane & 15, lg = lane >> 4;
    int id = blockIdx.x;

    if (id < 192) {
        // decode: XCD-grouped; 3 nb-blocks per (mb,s) share an A-panel on one XCD
        int xcd = id & 7, slot_ = id >> 3;   // slot_ 0..23
        int g = xcd * 8 + slot_ / 3;         // 0..63 = (mb, s)
        int nb = slot_ % 3;                  // col tile 0..2
        int mb = g >> 1, s = g & 1;
        int n0 = nb * 64;
        int m0 = mb * 128;
        int wm0 = (wid >> 1) * 64, wn0 = (wid & 1) * 32;

        for (int i = tid; i < 128 * KNB; i += 256)
            nbr[i] = (unsigned short)neighbors[(size_t)m0 * KNB + i];
        __syncthreads();

        f32x4 accK[4][2] = {}, accV[4][2] = {};

        auto stage = [&](int k0, int b) {
            #pragma unroll
            for (int it = 0; it < 4; ++it) {
                int idx = (wid * 4 + it) * 64 + lane;
                int m = idx >> 3, cs = (idx & 7) ^ (m & 7);
                int k = k0 + cs * 8;
                int slot = k >> 8, off = k & 255;
                int nbid = nbr[m * KNB + slot];
                const short* src;
                if (off < ED)
                    src = featbf + (size_t)nbid * ED + off;
                else if (off < ED + EFD)
                    src = edgebf + ((size_t)(m0 + m) * KNB + slot) * EFD + (off - ED);
                else
                    src = timebf + ((size_t)(m0 + m) * KNB + slot) * TD + (off - ED - EFD);
                gload_lds16(src, &As[b][(wid * 4 + it) * 512]);
            }
            #pragma unroll
            for (int it = 0; it < 2; ++it) {
                int idx = (wid * 2 + it) * 64 + lane;
                int n = idx >> 3, c = (idx & 7) ^ (n & 7);
                gload_lds16(WkT + (size_t)(n0 + n) * KDD + k0 + c * 8,
                            &Bs[b][0][(wid * 2 + it) * 512]);
            }
            #pragma unroll
            for (int it = 0; it < 2; ++it) {
                int idx = (wid * 2 + it) * 64 + lane;
                int n = idx >> 3, c = (idx & 7) ^ (n & 7);
                gload_lds16(WvT + (size_t)(n0 + n) * KDD + k0 + c * 8,
                            &Bs[b][1][(wid * 2 + it) * 512]);
            }
        };

        int kbase = s * (KDD / KVSPLIT);     // 1280 per split, 20 steps of 64
        stage(kbase, 0);
        for (int i = 0; i < 20; ++i) {
            int b = i & 1;
            __syncthreads();
            if (i < 19) stage(kbase + (i + 1) * 64, b ^ 1);
            #pragma unroll
            for (int ks = 0; ks < 2; ++ks) {
                bf16x8 af[4], bk8[2], bv8[2];
                #pragma unroll
                for (int mf = 0; mf < 4; ++mf) {
                    int m = wm0 + mf * 16 + lx;
                    af[mf] = *(const bf16x8*)&As[b][m * 64 + (((ks * 4 + lg) ^ (m & 7)) << 3)];
                }
                #pragma unroll
                for (int nf = 0; nf < 2; ++nf) {
                    int n = wn0 + nf * 16 + lx;
                    int o = n * 64 + (((ks * 4 + lg) ^ (n & 7)) << 3);
                    bk8[nf] = *(const bf16x8*)&Bs[b][0][o];
                    bv8[nf] = *(const bf16x8*)&Bs[b][1][o];
                }
                #pragma unroll
                for (int mf = 0; mf < 4; ++mf)
                    #pragma unroll
                    for (int nf = 0; nf < 2; ++nf) {
                        accK[mf][nf] = __builtin_amdgcn_mfma_f32_16x16x32_bf16(
                            af[mf], bk8[nf], accK[mf][nf], 0, 0, 0);
                        accV[mf][nf] = __builtin_amdgcn_mfma_f32_16x16x32_bf16(
                            af[mf], bv8[nf], accV[mf][nf], 0, 0, 0);
                    }
            }
        }
        #pragma unroll
        for (int nf = 0; nf < 2; ++nf) {
            int ncol = n0 + wn0 + nf * 16 + lx;
            #pragma unroll
            for (int mf = 0; mf < 4; ++mf) {
                int mrow = m0 + wm0 + mf * 16 + 4 * lg;
                #pragma unroll
                for (int r = 0; r < 4; ++r)
                    psumK[((size_t)s * NN + mrow + r) * DD + ncol] = f2bf(accK[mf][nf][r]);
                short4 s4;
                s4.x = f2bf(accV[mf][nf][0]); s4.y = f2bf(accV[mf][nf][1]);
                s4.z = f2bf(accV[mf][nf][2]); s4.w = f2bf(accV[mf][nf][3]);
                *(short4*)&psumV[((size_t)(s * DD + ncol)) * NN + mrow] = s4;
            }
        }
    } else {
        // ---- Q projection: qb = (x @ Wq[0:128] + bq) * scale ----
        int qid = id - 192;                 // 0..191
        int m0 = (qid / 3) * 64, n0 = (qid % 3) * 64;
        int wm0 = (wid >> 1) * 32, wn0 = (wid & 1) * 32;
        short* qAs = &As[0][0];
        short* qBs = &Bs[0][0][0];
        f32x4 acc[2][2] = {};

        for (int k0 = 0; k0 < ED; k0 += 64) {
            #pragma unroll
            for (int it = 0; it < 2; ++it) {
                int idx = (wid * 2 + it) * 64 + lane;
                int m = idx >> 3, c = (idx & 7) ^ (m & 7);
                gload_lds16(xb + (size_t)(m0 + m) * ED + k0 + c * 8, &qAs[(wid * 2 + it) * 512]);
            }
            #pragma unroll
            for (int it = 0; it < 2; ++it) {
                int idx = (wid * 2 + it) * 64 + lane;
                int n = idx >> 3, c = (idx & 7) ^ (n & 7);
                gload_lds16(WqT + (size_t)(n0 + n) * ED + k0 + c * 8, &qBs[(wid * 2 + it) * 512]);
            }
            __syncthreads();
            #pragma unroll
            for (int ks = 0; ks < 2; ++ks) {
                bf16x8 af[2], bfr[2];
                #pragma unroll
                for (int mf = 0; mf < 2; ++mf) {
                    int m = wm0 + mf * 16 + lx;
                    af[mf] = *(const bf16x8*)&qAs[m * 64 + (((ks * 4 + lg) ^ (m & 7)) << 3)];
                }
                #pragma unroll
                for (int nf = 0; nf < 2; ++nf) {
                    int n = wn0 + nf * 16 + lx;
                    bfr[nf] = *(const bf16x8*)&qBs[n * 64 + (((ks * 4 + lg) ^ (n & 7)) << 3)];
                }
                #pragma unroll
                for (int mf = 0; mf < 2; ++mf)
                    #pragma unroll
                    for (int nf = 0; nf < 2; ++nf)
                        acc[mf][nf] = __builtin_amdgcn_mfma_f32_16x16x32_bf16(
                            af[mf], bfr[nf], acc[mf][nf], 0, 0, 0);
            }
            __syncthreads();
        }
        const float scale = 0.10206207261596577f; // 1/sqrt(96), folded into q
        #pragma unroll
        for (int nf = 0; nf < 2; ++nf) {
            int ncol = n0 + wn0 + nf * 16 + lx;
            float bb = bq[ncol];
            #pragma unroll
            for (int mf = 0; mf < 2; ++mf) {
                int mrow = m0 + wm0 + mf * 16 + 4 * lg;
                #pragma unroll
                for (int r = 0; r < 4; ++r)
                    qb[(size_t)(mrow + r) * DD + ncol] = f2bf((acc[mf][nf][r] + bb) * scale);
            }
        }
    }
}

// ---------------- reduce K-splits (bf16 partials), add bias, cast bf16 ----------------
__global__ __launch_bounds__(256) void kv_combine(
    const short* __restrict__ psumK, const short* __restrict__ psumV,
    const float* __restrict__ bk, const float* __restrict__ bv,
    short* __restrict__ kk, short* __restrict__ vvT)
{
    const int HALF = NN * DD / 4;
    int i = blockIdx.x * 256 + threadIdx.x;
    if (i < HALF) {
        int base = i * 4, n = base % DD;
        float sum[4] = {0.f, 0.f, 0.f, 0.f};
        #pragma unroll
        for (int s = 0; s < KVSPLIT; ++s) {
            short4 v = *(const short4*)&psumK[(size_t)s * NN * DD + base];
            sum[0] += bf2f(v.x); sum[1] += bf2f(v.y);
            sum[2] += bf2f(v.z); sum[3] += bf2f(v.w);
        }
        float4 bb = *(const float4*)&bk[n];
        short4 o;
        o.x = f2bf(sum[0] + bb.x); o.y = f2bf(sum[1] + bb.y);
        o.z = f2bf(sum[2] + bb.z); o.w = f2bf(sum[3] + bb.w);
        *(short4*)&kk[base] = o;
    } else {
        int j = i - HALF;
        int base = j * 4, n = base / NN;
        float sum[4] = {0.f, 0.f, 0.f, 0.f};
        #pragma unroll
        for (int s = 0; s < KVSPLIT; ++s) {
            short4 v = *(const short4*)&psumV[(size_t)s * DD * NN + base];
            sum[0] += bf2f(v.x); sum[1] += bf2f(v.y);
            sum[2] += bf2f(v.z); sum[3] += bf2f(v.w);
        }
        float bb = bv[n];
        short4 o;
        o.x = f2bf(sum[0] + bb); o.y = f2bf(sum[1] + bb);
        o.z = f2bf(sum[2] + bb); o.w = f2bf(sum[3] + bb);
        *(short4*)&vvT[base] = o;
    }
}

// ---------------- flash attention, bf16 MFMA, no-max softmax, 8 waves ----------------
__global__ __launch_bounds__(512) void attn_mfma(
    const short* __restrict__ qb,      // [4096][192] bf16, pre-scaled
    const short* __restrict__ kk,      // [4096][192] bf16
    const short* __restrict__ vvT,     // [192][4096] bf16
    short* __restrict__ opart,         // [4][4096][192] bf16 unnormalized
    float* __restrict__ ml)            // [4][2][4096] l-sums
{
    __shared__ short Ks[2][64 * 96];
    __shared__ short Vs[2][96 * 64];
    __shared__ short Ps[8][16 * 72];
    int tid = threadIdx.x, wid = tid >> 6, lane = tid & 63;
    int lx = lane & 15, lg = lane >> 4;
    int h = blockIdx.y, split = blockIdx.z;
    int hoff = h * HD;
    int qb0 = blockIdx.x * 128 + wid * 16;

    bf16x8 qf[3];
    #pragma unroll
    for (int ks = 0; ks < 3; ++ks)
        qf[ks] = *(const bf16x8*)&qb[(size_t)(qb0 + lx) * DD + hoff + ks * 32 + lg * 8];

    auto stage = [&](int kb, int b) {
        #pragma unroll
        for (int jj = 0; jj < 3; ++jj) {
            int j = wid * 3 + jj;              // 0..23
            if (j < 12) {
                int idx = j * 64 + lane;
                int row = idx / 12, c = idx % 12;
                gload_lds16(kk + (size_t)(kb + row) * DD + hoff + c * 8,
                            &Ks[b][j * 512]);
            } else {
                int idx = (j - 12) * 64 + lane;
                int d = idx >> 3, c = (idx & 7) ^ (d & 7);
                gload_lds16(vvT + (size_t)(hoff + d) * NN + kb + c * 8,
                            &Vs[b][(j - 12) * 512]);
            }
        }
    };

    float lsum = 0.0f;
    f32x4 accO[6] = {};
    short* myP = &Ps[wid][0];
    int kbase = split * (NN / NSPLIT);

    stage(kbase, 0);

    for (int t = 0; t < 16; ++t) {
        int b = t & 1;
        __syncthreads();
        // prefetch FIRST: gives the loads the whole step to land before next barrier
        if (t < 15) stage(kbase + (t + 1) * 64, b ^ 1);
        f32x4 sf[4];
        #pragma unroll
        for (int nf = 0; nf < 4; ++nf) sf[nf] = (f32x4){0.f, 0.f, 0.f, 0.f};
        #pragma unroll
        for (int ks = 0; ks < 3; ++ks) {
            #pragma unroll
            for (int nf = 0; nf < 4; ++nf) {
                bf16x8 kf = *(const bf16x8*)&Ks[b][(nf * 16 + lx) * 96 + ks * 32 + lg * 8];
                sf[nf] = __builtin_amdgcn_mfma_f32_16x16x32_bf16(kf, qf[ks], sf[nf], 0, 0, 0);
            }
        }
        #pragma unroll
        for (int nf = 0; nf < 4; ++nf) {
            float p0 = __expf(sf[nf][0]);
            float p1 = __expf(sf[nf][1]);
            float p2 = __expf(sf[nf][2]);
            float p3 = __expf(sf[nf][3]);
            lsum += (p0 + p1) + (p2 + p3);
            unsigned int u0, u1;
            asm("v_cvt_pk_bf16_f32 %0, %1, %2" : "=v"(u0) : "v"(p0), "v"(p1));
            asm("v_cvt_pk_bf16_f32 %0, %1, %2" : "=v"(u1) : "v"(p2), "v"(p3));
            *(u32x2*)&myP[lx * 72 + nf * 16 + 4 * lg] = (u32x2){u0, u1};
        }
        #pragma unroll
        for (int kf2 = 0; kf2 < 2; ++kf2) {
            bf16x8 pf = *(const bf16x8*)&myP[lx * 72 + kf2 * 32 + lg * 8];
            #pragma unroll
            for (int nf2 = 0; nf2 < 6; ++nf2) {
                int d = nf2 * 16 + lx;
                bf16x8 vf = *(const bf16x8*)&Vs[b][d * 64 + (((kf2 * 4 + lg) ^ (d & 7)) << 3)];
                accO[nf2] = __builtin_amdgcn_mfma_f32_16x16x32_bf16(pf, vf, accO[nf2], 0, 0, 0);
            }
        }
    }

    short* op = opart + ((size_t)split * NN + qb0) * DD + hoff;
    #pragma unroll
    for (int nf2 = 0; nf2 < 6; ++nf2)
        #pragma unroll
        for (int r = 0; r < 4; ++r)
            op[(size_t)(4 * lg + r) * DD + nf2 * 16 + lx] = f2bf(accO[nf2][r]);
    lsum += __shfl_xor(lsum, 16);
    lsum += __shfl_xor(lsum, 32);
    if (lane < 16)
        ml[((size_t)(split * NH + h)) * NN + qb0 + lx] = lsum;
}

// ---------------- fused MLP: out = relu([x|ob] @ Wcat + bfold) @ W2 + b2 ----------------
__global__ __launch_bounds__(256) void mlp_fused(
    const short* __restrict__ xb,      // [4096][128] bf16
    const short* __restrict__ opart,   // [4][4096][192] bf16
    const float* __restrict__ ml,      // [4][2][4096] fp32
    const short* __restrict__ WcatT,   // [128][320] bf16
    const float* __restrict__ bfold,   // [128]
    const short* __restrict__ W2T,     // [128][128] bf16
    const float* __restrict__ b2,      // [128]
    float* __restrict__ out)           // [4096][128] fp32
{
    __shared__ short As[16 * 64];      // 2 KB
    __shared__ short Bs[128 * 64];     // 16 KB
    __shared__ short Ts[16 * 128];     // 4 KB
    __shared__ float linv[32];
    int tid = threadIdx.x, wid = tid >> 6, lane = tid & 63;
    int lx = lane & 15, lg = lane >> 4;
    int m0 = blockIdx.x * 16;
    int wn0 = wid * 32;

    if (tid < 32) {
        int rl = tid >> 1, hh = tid & 1;
        float l = 0.f;
        #pragma unroll
        for (int s = 0; s < NSPLIT; ++s) l += ml[(size_t)(s * NH + hh) * NN + m0 + rl];
        linv[tid] = 1.0f / l;
    }

    f32x4 acc[2] = {};
    for (int step = 0; step < 5; ++step) {
        int k0 = step * 64;
        if (step < 2) {
            if (wid < 2) {
                int idx = tid;             // 0..127
                int m = idx >> 3, c = (idx & 7) ^ (m & 7);
                gload_lds16(xb + (size_t)(m0 + m) * ED + k0 + c * 8, &As[wid * 512]);
            }
        } else {
            if (tid < 128) {
                int m = tid >> 3, j8 = tid & 7;
                int dg = (k0 - 128) + j8 * 8;  // global attn-dim base (head-uniform)
                float sum[8] = {};
                #pragma unroll
                for (int s = 0; s < NSPLIT; ++s) {
                    bf16x8 v = *(const bf16x8*)&opart[((size_t)s * NN + m0 + m) * DD + dg];
                    #pragma unroll
                    for (int j = 0; j < 8; ++j) sum[j] += bf2f(v[j]);
                }
                float inv = linv[m * 2 + (dg >= HD ? 1 : 0)];
                short tmp[8];
                #pragma unroll
                for (int j = 0; j < 8; ++j) tmp[j] = f2bf(sum[j] * inv);
                *(bf16x8*)&As[m * 64 + ((j8 ^ (m & 7)) << 3)] = *(bf16x8*)&tmp[0];
            }
        }
        #pragma unroll
        for (int it = 0; it < 4; ++it) {
            int idx = (wid * 4 + it) * 64 + lane;
            int n = idx >> 3, c = (idx & 7) ^ (n & 7);
            gload_lds16(WcatT + (size_t)n * 320 + k0 + c * 8, &Bs[(wid * 4 + it) * 512]);
        }
        __syncthreads();
        #pragma unroll
        for (int kss = 0; kss < 2; ++kss) {
            int m = lx;
            bf16x8 af = *(const bf16x8*)&As[m * 64 + (((kss * 4 + lg) ^ (m & 7)) << 3)];
            #pragma unroll
            for (int nf = 0; nf < 2; ++nf) {
                int n = wn0 + nf * 16 + lx;
                bf16x8 bfr = *(const bf16x8*)&Bs[n * 64 + (((kss * 4 + lg) ^ (n & 7)) << 3)];
                acc[nf] = __builtin_amdgcn_mfma_f32_16x16x32_bf16(af, bfr, acc[nf], 0, 0, 0);
            }
        }
        __syncthreads();
    }
    // t = relu(acc + bfold) -> Ts swizzled
    #pragma unroll
    for (int nf = 0; nf < 2; ++nf) {
        int kcol = wn0 + nf * 16 + lx;
        float bb = bfold[kcol];
        #pragma unroll
        for (int r = 0; r < 4; ++r) {
            int m = 4 * lg + r;
            float v = fmaxf(acc[nf][r] + bb, 0.f);
            Ts[m * 128 + ((((kcol >> 3) ^ (m & 7)) << 3) | (kcol & 7))] = f2bf(v);
        }
    }
    __syncthreads();
    // out = t @ W2 + b2
    f32x4 acc2[2] = {};
    #pragma unroll
    for (int step = 0; step < 2; ++step) {
        int k0 = step * 64;
        #pragma unroll
        for (int it = 0; it < 4; ++it) {
            int idx = (wid * 4 + it) * 64 + lane;
            int n = idx >> 3, c = (idx & 7) ^ (n & 7);
            gload_lds16(W2T + (size_t)n * 128 + k0 + c * 8, &Bs[(wid * 4 + it) * 512]);
        }
        __syncthreads();
        #pragma unroll
        for (int kss = 0; kss < 2; ++kss) {
            int m = lx;
            int chunk = step * 8 + kss * 4 + lg;
            bf16x8 af = *(const bf16x8*)&Ts[m * 128 + ((chunk ^ (m & 7)) << 3)];
            #pragma unroll
            for (int nf = 0; nf < 2; ++nf) {
                int n = wn0 + nf * 16 + lx;
                bf16x8 bfr = *(const bf16x8*)&Bs[n * 64 + (((kss * 4 + lg) ^ (n & 7)) << 3)];
                acc2[nf] = __builtin_amdgcn_mfma_f32_16x16x32_bf16(af, bfr, acc2[nf], 0, 0, 0);
            }
        }
        __syncthreads();
    }
    #pragma unroll
    for (int nf = 0; nf < 2; ++nf) {
        int ncol = wn0 + nf * 16 + lx;
        float bb = b2[ncol];
        #pragma unroll
        for (int r = 0; r < 4; ++r)
            out[(size_t)(m0 + 4 * lg + r) * 128 + ncol] = acc2[nf][r] + bb;
    }
}

extern "C" void kernel_launch(void* const* d_in, const int* in_sizes, int n_in,
                              void* d_out, int out_size, void* d_ws, size_t ws_size,
                              hipStream_t stream) {
    const float* features   = (const float*)d_in[0];
    const float* edge_feats = (const float*)d_in[1];
    const float* time_feats = (const float*)d_in[2];
    const int*   neighbors  = (const int*)d_in[3];
    const int*   node_idx   = (const int*)d_in[4];
    const float* Wq = (const float*)d_in[5];
    const float* bq = (const float*)d_in[6];
    const float* Wk = (const float*)d_in[7];
    const float* bk = (const float*)d_in[8];
    const float* Wv = (const float*)d_in[9];
    const float* bv = (const float*)d_in[10];
    const float* Wo = (const float*)d_in[11];
    const float* bo = (const float*)d_in[12];
    const float* W1 = (const float*)d_in[13];
    const float* b1 = (const float*)d_in[14];
    const float* W2 = (const float*)d_in[15];
    const float* b2 = (const float*)d_in[16];
    float* out = (float*)d_out;

    char* w = (char*)d_ws;
    short* featbf = (short*)w;  w += (size_t)NN * ED * 2;
    short* xb     = (short*)w;  w += (size_t)NN * ED * 2;
    short* edgebf = (short*)w;  w += (size_t)NN * KNB * EFD * 2;
    short* timebf = (short*)w;  w += (size_t)NN * KNB * TD * 2;
    short* qb     = (short*)w;  w += (size_t)NN * DD * 2;
    short* kkb    = (short*)w;  w += (size_t)NN * DD * 2;
    short* vvT    = (short*)w;  w += (size_t)DD * NN * 2;
    short* WkT    = (short*)w;  w += (size_t)DD * KDD * 2;
    short* WvT    = (short*)w;  w += (size_t)DD * KDD * 2;
    short* WqT    = (short*)w;  w += (size_t)DD * ED * 2;
    short* WcatT  = (short*)w;  w += (size_t)ED * 320 * 2;
    short* W2T    = (short*)w;  w += (size_t)ED * ED * 2;
    float* bfold  = (float*)w;  w += (size_t)ED * 4;
    short* psumK  = (short*)w;  w += (size_t)KVSPLIT * NN * DD * 2;
    short* psumV  = (short*)w;  w += (size_t)KVSPLIT * DD * NN * 2;
    short* opart  = (short*)w;  w += (size_t)NSPLIT * NN * DD * 2;
    float* ml     = (float*)w;  w += (size_t)NSPLIT * NH * NN * 4;

    prep_convert<<<6591, 256, 0, stream>>>(
        Wk, Wv, Wq, Wo, bo, W1, b1, W2,
        features, edge_feats, time_feats, node_idx,
        WkT, WvT, WqT, WcatT, W2T, bfold, featbf, xb, edgebf, timebf);
    kvq_gemm_mfma<<<192 + 192, 256, 0, stream>>>(
        featbf, edgebf, timebf, neighbors, WkT, WvT, psumK, psumV, xb, WqT, bq, qb);
    kv_combine<<<2 * NN * DD / 4 / 256, 256, 0, stream>>>(psumK, psumV, bk, bv, kkb, vvT);
    attn_mfma<<<dim3(NN / 128, NH, NSPLIT), 512, 0, stream>>>(qb, kkb, vvT, opart, ml);
    mlp_fused<<<NN / 16, 256, 0, stream>>>(xb, opart, ml, WcatT, bfold, W2T, b2, out);
}

// Round 20
// 67.412 us; speedup vs baseline: 1.0288x; 1.0288x over previous
//
#include <hip/hip_runtime.h>
#include <hip/hip_bf16.h>
#include <math.h>

#define NN   4096
#define KNB  10
#define ED   128
#define EFD  64
#define TD   64
#define DD   192     // E + T
#define KEYD 256     // E + EF + T
#define KDD  2560    // KEYD * KNB
#define HD   96      // DD / H
#define NH   2
#define NSPLIT 4     // K-splits for kv gemm and key-splits for attention

typedef __attribute__((ext_vector_type(8))) short bf16x8;
typedef __attribute__((ext_vector_type(4))) float f32x4;
typedef __attribute__((ext_vector_type(2))) unsigned int u32x2;

__device__ inline short f2bf(float f) {
    union { float f; unsigned int u; } c; c.f = f;
    unsigned int r = (c.u + 0x7FFFu + ((c.u >> 16) & 1u)) >> 16;
    return (short)r;
}

__device__ inline float bf2f(short s) {
    union { unsigned int u; float f; } c;
    c.u = ((unsigned int)(unsigned short)s) << 16;
    return c.f;
}

__device__ inline void gload_lds16(const void* g, void* lds) {
    __builtin_amdgcn_global_load_lds(
        (const __attribute__((address_space(1))) void*)g,
        (__attribute__((address_space(3))) void*)lds, 16, 0, 0);
}

// ---------------- merged prep: transposes + MLP fold + bf16 conversions ----------------
__global__ __launch_bounds__(256) void prep_convert(
    const float* __restrict__ Wk, const float* __restrict__ Wv,
    const float* __restrict__ Wq,
    const float* __restrict__ Wo, const float* __restrict__ bo,
    const float* __restrict__ W1, const float* __restrict__ b1,
    const float* __restrict__ W2,
    const float* __restrict__ features, const float* __restrict__ edge_feats,
    const float* __restrict__ time_feats, const int* __restrict__ node_idx,
    short* __restrict__ WkT, short* __restrict__ WvT, short* __restrict__ WqT,
    short* __restrict__ WcatT, short* __restrict__ W2T, float* __restrict__ bfold,
    short* __restrict__ featbf, short* __restrict__ xb,
    short* __restrict__ edgebf, short* __restrict__ timebf)
{
    int blk = blockIdx.x, t = threadIdx.x;
    if (blk < 254) {
        __shared__ float ts[64][65];
        const float* W; short* WT; int src_ld, dst_ld, k0, n0;
        if (blk < 240) {            // Wk / Wv : [2560][192] -> [192][2560]
            int z = blk / 120, r = blk % 120;
            W = z ? Wv : Wk; WT = z ? WvT : WkT;
            src_ld = DD; dst_ld = KDD; k0 = (r % 40) * 64; n0 = (r / 40) * 64;
        } else if (blk < 246) {     // Wq : [128][192] -> [192][128]
            int r = blk - 240;
            W = Wq; WT = WqT; src_ld = DD; dst_ld = ED;
            k0 = (r % 2) * 64; n0 = (r / 2) * 64;
        } else if (blk < 250) {     // W1 rows 0..127 -> WcatT[:, 0:128] (ld 320)
            int r = blk - 246;
            W = W1; WT = WcatT; src_ld = ED; dst_ld = 320;
            k0 = (r % 2) * 64; n0 = (r / 2) * 64;
        } else {                    // W2 : [128][128] -> W2T
            int r = blk - 250;
            W = W2; WT = W2T; src_ld = ED; dst_ld = ED;
            k0 = (r % 2) * 64; n0 = (r / 2) * 64;
        }
        #pragma unroll
        for (int j = 0; j < 4; ++j) {
            int k = (t >> 4) + j * 16, n4 = (t & 15) * 4;
            float4 v = *(const float4*)&W[(size_t)(k0 + k) * src_ld + n0 + n4];
            ts[k][n4] = v.x; ts[k][n4 + 1] = v.y; ts[k][n4 + 2] = v.z; ts[k][n4 + 3] = v.w;
        }
        __syncthreads();
        int n = t >> 2, kc = (t & 3) * 16;
        short tmp[16];
        #pragma unroll
        for (int j = 0; j < 16; ++j) tmp[j] = f2bf(ts[kc + j][n]);
        *(bf16x8*)&WT[(size_t)(n0 + n) * dst_ld + k0 + kc] = *(bf16x8*)&tmp[0];
        *(bf16x8*)&WT[(size_t)(n0 + n) * dst_ld + k0 + kc + 8] = *(bf16x8*)&tmp[8];
    } else if (blk == 254) {
        if (t < 128) {
            float s = 0.f;
            for (int j = 0; j < DD; ++j) s += bo[j] * W1[(size_t)(ED + j) * ED + t];
            bfold[t] = s + b1[t];
        }
    } else if (blk < 447) {
        int d = blk - 255;              // 0..191
        if (t < 128) {
            float s = 0.f;
            for (int j = 0; j < DD; ++j)
                s += Wo[(size_t)d * DD + j] * W1[(size_t)(ED + j) * ED + t];
            WcatT[t * 320 + ED + d] = f2bf(s);
        }
    } else {
        int cb = blk - 447;             // 0..6143
        if (cb < 512) {                 // features -> featbf
            int e4 = cb * 256 + t;
            float4 v = *(const float4*)&features[(size_t)e4 * 4];
            short4 o; o.x = f2bf(v.x); o.y = f2bf(v.y); o.z = f2bf(v.z); o.w = f2bf(v.w);
            *(short4*)&featbf[(size_t)e4 * 4] = o;
        } else if (cb < 1024) {         // features[node_idx] -> xb
            int l4 = (cb - 512) * 256 + t;
            int n = l4 >> 5, c = (l4 & 31) * 4;
            float4 v = *(const float4*)&features[(size_t)node_idx[n] * ED + c];
            short4 o; o.x = f2bf(v.x); o.y = f2bf(v.y); o.z = f2bf(v.z); o.w = f2bf(v.w);
            *(short4*)&xb[(size_t)n * ED + c] = o;
        } else if (cb < 3584) {         // edge_feats -> edgebf
            int l4 = (cb - 1024) * 256 + t;
            float4 v = *(const float4*)&edge_feats[(size_t)l4 * 4];
            short4 o; o.x = f2bf(v.x); o.y = f2bf(v.y); o.z = f2bf(v.z); o.w = f2bf(v.w);
            *(short4*)&edgebf[(size_t)l4 * 4] = o;
        } else {                        // time_feats -> timebf
            int l4 = (cb - 3584) * 256 + t;
            float4 v = *(const float4*)&time_feats[(size_t)l4 * 4];
            short4 o; o.x = f2bf(v.x); o.y = f2bf(v.y); o.z = f2bf(v.z); o.w = f2bf(v.w);
            *(short4*)&timebf[(size_t)l4 * 4] = o;
        }
    }
}

// ---------------- K+V paired projection (direct gather, K-split x4) + Q projection ----------
// ids 0..383: kv blocks (each computes BOTH K and V 64-col tiles; A staged once).
// ids 384..575: q blocks.
__global__ __launch_bounds__(256) void kvq_gemm_mfma(
    const short* __restrict__ featbf, const short* __restrict__ edgebf,
    const short* __restrict__ timebf, const int* __restrict__ neighbors,
    const short* __restrict__ WkT, const short* __restrict__ WvT,
    short* __restrict__ psumK, short* __restrict__ psumV,
    const short* __restrict__ xb, const short* __restrict__ WqT,
    const float* __restrict__ bq, short* __restrict__ qb)
{
    __shared__ short As[2][128 * 64];        // 32 KB
    __shared__ short Bs[2][2][64 * 64];      // [dbuf][K=0/V=1] 32 KB
    __shared__ unsigned short nbr[128 * KNB];
    int tid = threadIdx.x, wid = tid >> 6, lane = tid & 63;
    int lx = lane & 15, lg = lane >> 4;
    int id = blockIdx.x;

    if (id < 384) {
        // decode: XCD-grouped; 3 nb-blocks per (mb,s) share an A-panel on one XCD
        int xcd = id & 7, slot_ = id >> 3;   // slot_ 0..47
        int g = xcd * 16 + slot_ / 3;        // 0..127 = (mb, s)
        int nb = slot_ % 3;                  // col tile 0..2
        int mb = g >> 2, s = g & 3;
        int n0 = nb * 64;
        int m0 = mb * 128;
        int wm0 = (wid >> 1) * 64, wn0 = (wid & 1) * 32;

        for (int i = tid; i < 128 * KNB; i += 256)
            nbr[i] = (unsigned short)neighbors[(size_t)m0 * KNB + i];
        __syncthreads();

        f32x4 accK[4][2] = {}, accV[4][2] = {};

        auto stage = [&](int k0, int b) {
            #pragma unroll
            for (int it = 0; it < 4; ++it) {
                int idx = (wid * 4 + it) * 64 + lane;
                int m = idx >> 3, cs = (idx & 7) ^ (m & 7);
                int k = k0 + cs * 8;
                int slot = k >> 8, off = k & 255;
                int nbid = nbr[m * KNB + slot];
                const short* src;
                if (off < ED)
                    src = featbf + (size_t)nbid * ED + off;
                else if (off < ED + EFD)
                    src = edgebf + ((size_t)(m0 + m) * KNB + slot) * EFD + (off - ED);
                else
                    src = timebf + ((size_t)(m0 + m) * KNB + slot) * TD + (off - ED - EFD);
                gload_lds16(src, &As[b][(wid * 4 + it) * 512]);
            }
            #pragma unroll
            for (int it = 0; it < 2; ++it) {
                int idx = (wid * 2 + it) * 64 + lane;
                int n = idx >> 3, c = (idx & 7) ^ (n & 7);
                gload_lds16(WkT + (size_t)(n0 + n) * KDD + k0 + c * 8,
                            &Bs[b][0][(wid * 2 + it) * 512]);
            }
            #pragma unroll
            for (int it = 0; it < 2; ++it) {
                int idx = (wid * 2 + it) * 64 + lane;
                int n = idx >> 3, c = (idx & 7) ^ (n & 7);
                gload_lds16(WvT + (size_t)(n0 + n) * KDD + k0 + c * 8,
                            &Bs[b][1][(wid * 2 + it) * 512]);
            }
        };

        int kbase = s * (KDD / NSPLIT);
        stage(kbase, 0);
        for (int i = 0; i < 10; ++i) {
            int b = i & 1;
            __syncthreads();
            if (i < 9) stage(kbase + (i + 1) * 64, b ^ 1);
            #pragma unroll
            for (int ks = 0; ks < 2; ++ks) {
                bf16x8 af[4], bk8[2], bv8[2];
                #pragma unroll
                for (int mf = 0; mf < 4; ++mf) {
                    int m = wm0 + mf * 16 + lx;
                    af[mf] = *(const bf16x8*)&As[b][m * 64 + (((ks * 4 + lg) ^ (m & 7)) << 3)];
                }
                #pragma unroll
                for (int nf = 0; nf < 2; ++nf) {
                    int n = wn0 + nf * 16 + lx;
                    int o = n * 64 + (((ks * 4 + lg) ^ (n & 7)) << 3);
                    bk8[nf] = *(const bf16x8*)&Bs[b][0][o];
                    bv8[nf] = *(const bf16x8*)&Bs[b][1][o];
                }
                #pragma unroll
                for (int mf = 0; mf < 4; ++mf)
                    #pragma unroll
                    for (int nf = 0; nf < 2; ++nf) {
                        accK[mf][nf] = __builtin_amdgcn_mfma_f32_16x16x32_bf16(
                            af[mf], bk8[nf], accK[mf][nf], 0, 0, 0);
                        accV[mf][nf] = __builtin_amdgcn_mfma_f32_16x16x32_bf16(
                            af[mf], bv8[nf], accV[mf][nf], 0, 0, 0);
                    }
            }
        }
        #pragma unroll
        for (int nf = 0; nf < 2; ++nf) {
            int ncol = n0 + wn0 + nf * 16 + lx;
            #pragma unroll
            for (int mf = 0; mf < 4; ++mf) {
                int mrow = m0 + wm0 + mf * 16 + 4 * lg;
                #pragma unroll
                for (int r = 0; r < 4; ++r)
                    psumK[((size_t)s * NN + mrow + r) * DD + ncol] = f2bf(accK[mf][nf][r]);
                short4 s4;
                s4.x = f2bf(accV[mf][nf][0]); s4.y = f2bf(accV[mf][nf][1]);
                s4.z = f2bf(accV[mf][nf][2]); s4.w = f2bf(accV[mf][nf][3]);
                *(short4*)&psumV[((size_t)(s * DD + ncol)) * NN + mrow] = s4;
            }
        }
    } else {
        // ---- Q projection: qb = (x @ Wq[0:128] + bq) * scale ----
        int qid = id - 384;                 // 0..191
        int m0 = (qid / 3) * 64, n0 = (qid % 3) * 64;
        int wm0 = (wid >> 1) * 32, wn0 = (wid & 1) * 32;
        short* qAs = &As[0][0];
        short* qBs = &Bs[0][0][0];
        f32x4 acc[2][2] = {};

        for (int k0 = 0; k0 < ED; k0 += 64) {
            #pragma unroll
            for (int it = 0; it < 2; ++it) {
                int idx = (wid * 2 + it) * 64 + lane;
                int m = idx >> 3, c = (idx & 7) ^ (m & 7);
                gload_lds16(xb + (size_t)(m0 + m) * ED + k0 + c * 8, &qAs[(wid * 2 + it) * 512]);
            }
            #pragma unroll
            for (int it = 0; it < 2; ++it) {
                int idx = (wid * 2 + it) * 64 + lane;
                int n = idx >> 3, c = (idx & 7) ^ (n & 7);
                gload_lds16(WqT + (size_t)(n0 + n) * ED + k0 + c * 8, &qBs[(wid * 2 + it) * 512]);
            }
            __syncthreads();
            #pragma unroll
            for (int ks = 0; ks < 2; ++ks) {
                bf16x8 af[2], bfr[2];
                #pragma unroll
                for (int mf = 0; mf < 2; ++mf) {
                    int m = wm0 + mf * 16 + lx;
                    af[mf] = *(const bf16x8*)&qAs[m * 64 + (((ks * 4 + lg) ^ (m & 7)) << 3)];
                }
                #pragma unroll
                for (int nf = 0; nf < 2; ++nf) {
                    int n = wn0 + nf * 16 + lx;
                    bfr[nf] = *(const bf16x8*)&qBs[n * 64 + (((ks * 4 + lg) ^ (n & 7)) << 3)];
                }
                #pragma unroll
                for (int mf = 0; mf < 2; ++mf)
                    #pragma unroll
                    for (int nf = 0; nf < 2; ++nf)
                        acc[mf][nf] = __builtin_amdgcn_mfma_f32_16x16x32_bf16(
                            af[mf], bfr[nf], acc[mf][nf], 0, 0, 0);
            }
            __syncthreads();
        }
        const float scale = 0.10206207261596577f; // 1/sqrt(96), folded into q
        #pragma unroll
        for (int nf = 0; nf < 2; ++nf) {
            int ncol = n0 + wn0 + nf * 16 + lx;
            float bb = bq[ncol];
            #pragma unroll
            for (int mf = 0; mf < 2; ++mf) {
                int mrow = m0 + wm0 + mf * 16 + 4 * lg;
                #pragma unroll
                for (int r = 0; r < 4; ++r)
                    qb[(size_t)(mrow + r) * DD + ncol] = f2bf((acc[mf][nf][r] + bb) * scale);
            }
        }
    }
}

// ---------------- reduce K-splits (bf16 partials), add bias, cast bf16 ----------------
__global__ __launch_bounds__(256) void kv_combine(
    const short* __restrict__ psumK, const short* __restrict__ psumV,
    const float* __restrict__ bk, const float* __restrict__ bv,
    short* __restrict__ kk, short* __restrict__ vvT)
{
    const int HALF = NN * DD / 4;
    int i = blockIdx.x * 256 + threadIdx.x;
    if (i < HALF) {
        int base = i * 4, n = base % DD;
        float sum[4] = {0.f, 0.f, 0.f, 0.f};
        #pragma unroll
        for (int s = 0; s < NSPLIT; ++s) {
            short4 v = *(const short4*)&psumK[(size_t)s * NN * DD + base];
            sum[0] += bf2f(v.x); sum[1] += bf2f(v.y);
            sum[2] += bf2f(v.z); sum[3] += bf2f(v.w);
        }
        float4 bb = *(const float4*)&bk[n];
        short4 o;
        o.x = f2bf(sum[0] + bb.x); o.y = f2bf(sum[1] + bb.y);
        o.z = f2bf(sum[2] + bb.z); o.w = f2bf(sum[3] + bb.w);
        *(short4*)&kk[base] = o;
    } else {
        int j = i - HALF;
        int base = j * 4, n = base / NN;
        float sum[4] = {0.f, 0.f, 0.f, 0.f};
        #pragma unroll
        for (int s = 0; s < NSPLIT; ++s) {
            short4 v = *(const short4*)&psumV[(size_t)s * DD * NN + base];
            sum[0] += bf2f(v.x); sum[1] += bf2f(v.y);
            sum[2] += bf2f(v.z); sum[3] += bf2f(v.w);
        }
        float bb = bv[n];
        short4 o;
        o.x = f2bf(sum[0] + bb); o.y = f2bf(sum[1] + bb);
        o.z = f2bf(sum[2] + bb); o.w = f2bf(sum[3] + bb);
        *(short4*)&vvT[base] = o;
    }
}

// ---------------- flash attention, bf16 MFMA, no-max softmax, 8 waves ----------------
__global__ __launch_bounds__(512) void attn_mfma(
    const short* __restrict__ qb,      // [4096][192] bf16, pre-scaled
    const short* __restrict__ kk,      // [4096][192] bf16
    const short* __restrict__ vvT,     // [192][4096] bf16
    short* __restrict__ opart,         // [4][4096][192] bf16 unnormalized
    float* __restrict__ ml)            // [4][2][4096] l-sums
{
    __shared__ short Ks[2][64 * 96];
    __shared__ short Vs[2][96 * 64];
    __shared__ short Ps[8][16 * 72];
    int tid = threadIdx.x, wid = tid >> 6, lane = tid & 63;
    int lx = lane & 15, lg = lane >> 4;
    int h = blockIdx.y, split = blockIdx.z;
    int hoff = h * HD;
    int qb0 = blockIdx.x * 128 + wid * 16;

    bf16x8 qf[3];
    #pragma unroll
    for (int ks = 0; ks < 3; ++ks)
        qf[ks] = *(const bf16x8*)&qb[(size_t)(qb0 + lx) * DD + hoff + ks * 32 + lg * 8];

    auto stage = [&](int kb, int b) {
        #pragma unroll
        for (int jj = 0; jj < 3; ++jj) {
            int j = wid * 3 + jj;              // 0..23
            if (j < 12) {
                int idx = j * 64 + lane;
                int row = idx / 12, c = idx % 12;
                gload_lds16(kk + (size_t)(kb + row) * DD + hoff + c * 8,
                            &Ks[b][j * 512]);
            } else {
                int idx = (j - 12) * 64 + lane;
                int d = idx >> 3, c = (idx & 7) ^ (d & 7);
                gload_lds16(vvT + (size_t)(hoff + d) * NN + kb + c * 8,
                            &Vs[b][(j - 12) * 512]);
            }
        }
    };

    float lsum = 0.0f;
    f32x4 accO[6] = {};
    short* myP = &Ps[wid][0];
    int kbase = split * (NN / NSPLIT);

    stage(kbase, 0);

    for (int t = 0; t < 16; ++t) {
        int b = t & 1;
        __syncthreads();
        // prefetch FIRST: gives the loads the whole step to land before next barrier
        if (t < 15) stage(kbase + (t + 1) * 64, b ^ 1);
        f32x4 sf[4];
        #pragma unroll
        for (int nf = 0; nf < 4; ++nf) sf[nf] = (f32x4){0.f, 0.f, 0.f, 0.f};
        #pragma unroll
        for (int ks = 0; ks < 3; ++ks) {
            #pragma unroll
            for (int nf = 0; nf < 4; ++nf) {
                bf16x8 kf = *(const bf16x8*)&Ks[b][(nf * 16 + lx) * 96 + ks * 32 + lg * 8];
                sf[nf] = __builtin_amdgcn_mfma_f32_16x16x32_bf16(kf, qf[ks], sf[nf], 0, 0, 0);
            }
        }
        #pragma unroll
        for (int nf = 0; nf < 4; ++nf) {
            float p0 = __expf(sf[nf][0]);
            float p1 = __expf(sf[nf][1]);
            float p2 = __expf(sf[nf][2]);
            float p3 = __expf(sf[nf][3]);
            lsum += (p0 + p1) + (p2 + p3);
            unsigned int u0, u1;
            asm("v_cvt_pk_bf16_f32 %0, %1, %2" : "=v"(u0) : "v"(p0), "v"(p1));
            asm("v_cvt_pk_bf16_f32 %0, %1, %2" : "=v"(u1) : "v"(p2), "v"(p3));
            *(u32x2*)&myP[lx * 72 + nf * 16 + 4 * lg] = (u32x2){u0, u1};
        }
        #pragma unroll
        for (int kf2 = 0; kf2 < 2; ++kf2) {
            bf16x8 pf = *(const bf16x8*)&myP[lx * 72 + kf2 * 32 + lg * 8];
            #pragma unroll
            for (int nf2 = 0; nf2 < 6; ++nf2) {
                int d = nf2 * 16 + lx;
                bf16x8 vf = *(const bf16x8*)&Vs[b][d * 64 + (((kf2 * 4 + lg) ^ (d & 7)) << 3)];
                accO[nf2] = __builtin_amdgcn_mfma_f32_16x16x32_bf16(pf, vf, accO[nf2], 0, 0, 0);
            }
        }
    }

    short* op = opart + ((size_t)split * NN + qb0) * DD + hoff;
    #pragma unroll
    for (int nf2 = 0; nf2 < 6; ++nf2)
        #pragma unroll
        for (int r = 0; r < 4; ++r)
            op[(size_t)(4 * lg + r) * DD + nf2 * 16 + lx] = f2bf(accO[nf2][r]);
    lsum += __shfl_xor(lsum, 16);
    lsum += __shfl_xor(lsum, 32);
    if (lane < 16)
        ml[((size_t)(split * NH + h)) * NN + qb0 + lx] = lsum;
}

// ---------------- fused MLP: out = relu([x|ob] @ Wcat + bfold) @ W2 + b2 ----------------
__global__ __launch_bounds__(256) void mlp_fused(
    const short* __restrict__ xb,      // [4096][128] bf16
    const short* __restrict__ opart,   // [4][4096][192] bf16
    const float* __restrict__ ml,      // [4][2][4096] fp32
    const short* __restrict__ WcatT,   // [128][320] bf16
    const float* __restrict__ bfold,   // [128]
    const short* __restrict__ W2T,     // [128][128] bf16
    const float* __restrict__ b2,      // [128]
    float* __restrict__ out)           // [4096][128] fp32
{
    __shared__ short As[16 * 64];      // 2 KB
    __shared__ short Bs[128 * 64];     // 16 KB
    __shared__ short Ts[16 * 128];     // 4 KB
    __shared__ float linv[32];
    int tid = threadIdx.x, wid = tid >> 6, lane = tid & 63;
    int lx = lane & 15, lg = lane >> 4;
    int m0 = blockIdx.x * 16;
    int wn0 = wid * 32;

    if (tid < 32) {
        int rl = tid >> 1, hh = tid & 1;
        float l = 0.f;
        #pragma unroll
        for (int s = 0; s < NSPLIT; ++s) l += ml[(size_t)(s * NH + hh) * NN + m0 + rl];
        linv[tid] = 1.0f / l;
    }

    f32x4 acc[2] = {};
    for (int step = 0; step < 5; ++step) {
        int k0 = step * 64;
        if (step < 2) {
            if (wid < 2) {
                int idx = tid;             // 0..127
                int m = idx >> 3, c = (idx & 7) ^ (m & 7);
                gload_lds16(xb + (size_t)(m0 + m) * ED + k0 + c * 8, &As[wid * 512]);
            }
        } else {
            if (tid < 128) {
                int m = tid >> 3, j8 = tid & 7;
                int dg = (k0 - 128) + j8 * 8;  // global attn-dim base (head-uniform)
                float sum[8] = {};
                #pragma unroll
                for (int s = 0; s < NSPLIT; ++s) {
                    bf16x8 v = *(const bf16x8*)&opart[((size_t)s * NN + m0 + m) * DD + dg];
                    #pragma unroll
                    for (int j = 0; j < 8; ++j) sum[j] += bf2f(v[j]);
                }
                float inv = linv[m * 2 + (dg >= HD ? 1 : 0)];
                short tmp[8];
                #pragma unroll
                for (int j = 0; j < 8; ++j) tmp[j] = f2bf(sum[j] * inv);
                *(bf16x8*)&As[m * 64 + ((j8 ^ (m & 7)) << 3)] = *(bf16x8*)&tmp[0];
            }
        }
        #pragma unroll
        for (int it = 0; it < 4; ++it) {
            int idx = (wid * 4 + it) * 64 + lane;
            int n = idx >> 3, c = (idx & 7) ^ (n & 7);
            gload_lds16(WcatT + (size_t)n * 320 + k0 + c * 8, &Bs[(wid * 4 + it) * 512]);
        }
        __syncthreads();
        #pragma unroll
        for (int kss = 0; kss < 2; ++kss) {
            int m = lx;
            bf16x8 af = *(const bf16x8*)&As[m * 64 + (((kss * 4 + lg) ^ (m & 7)) << 3)];
            #pragma unroll
            for (int nf = 0; nf < 2; ++nf) {
                int n = wn0 + nf * 16 + lx;
                bf16x8 bfr = *(const bf16x8*)&Bs[n * 64 + (((kss * 4 + lg) ^ (n & 7)) << 3)];
                acc[nf] = __builtin_amdgcn_mfma_f32_16x16x32_bf16(af, bfr, acc[nf], 0, 0, 0);
            }
        }
        __syncthreads();
    }
    // t = relu(acc + bfold) -> Ts swizzled
    #pragma unroll
    for (int nf = 0; nf < 2; ++nf) {
        int kcol = wn0 + nf * 16 + lx;
        float bb = bfold[kcol];
        #pragma unroll
        for (int r = 0; r < 4; ++r) {
            int m = 4 * lg + r;
            float v = fmaxf(acc[nf][r] + bb, 0.f);
            Ts[m * 128 + ((((kcol >> 3) ^ (m & 7)) << 3) | (kcol & 7))] = f2bf(v);
        }
    }
    __syncthreads();
    // out = t @ W2 + b2
    f32x4 acc2[2] = {};
    #pragma unroll
    for (int step = 0; step < 2; ++step) {
        int k0 = step * 64;
        #pragma unroll
        for (int it = 0; it < 4; ++it) {
            int idx = (wid * 4 + it) * 64 + lane;
            int n = idx >> 3, c = (idx & 7) ^ (n & 7);
            gload_lds16(W2T + (size_t)n * 128 + k0 + c * 8, &Bs[(wid * 4 + it) * 512]);
        }
        __syncthreads();
        #pragma unroll
        for (int kss = 0; kss < 2; ++kss) {
            int m = lx;
            int chunk = step * 8 + kss * 4 + lg;
            bf16x8 af = *(const bf16x8*)&Ts[m * 128 + ((chunk ^ (m & 7)) << 3)];
            #pragma unroll
            for (int nf = 0; nf < 2; ++nf) {
                int n = wn0 + nf * 16 + lx;
                bf16x8 bfr = *(const bf16x8*)&Bs[n * 64 + (((kss * 4 + lg) ^ (n & 7)) << 3)];
                acc2[nf] = __builtin_amdgcn_mfma_f32_16x16x32_bf16(af, bfr, acc2[nf], 0, 0, 0);
            }
        }
        __syncthreads();
    }
    #pragma unroll
    for (int nf = 0; nf < 2; ++nf) {
        int ncol = wn0 + nf * 16 + lx;
        float bb = b2[ncol];
        #pragma unroll
        for (int r = 0; r < 4; ++r)
            out[(size_t)(m0 + 4 * lg + r) * 128 + ncol] = acc2[nf][r] + bb;
    }
}

extern "C" void kernel_launch(void* const* d_in, const int* in_sizes, int n_in,
                              void* d_out, int out_size, void* d_ws, size_t ws_size,
                              hipStream_t stream) {
    const float* features   = (const float*)d_in[0];
    const float* edge_feats = (const float*)d_in[1];
    const float* time_feats = (const float*)d_in[2];
    const int*   neighbors  = (const int*)d_in[3];
    const int*   node_idx   = (const int*)d_in[4];
    const float* Wq = (const float*)d_in[5];
    const float* bq = (const float*)d_in[6];
    const float* Wk = (const float*)d_in[7];
    const float* bk = (const float*)d_in[8];
    const float* Wv = (const float*)d_in[9];
    const float* bv = (const float*)d_in[10];
    const float* Wo = (const float*)d_in[11];
    const float* bo = (const float*)d_in[12];
    const float* W1 = (const float*)d_in[13];
    const float* b1 = (const float*)d_in[14];
    const float* W2 = (const float*)d_in[15];
    const float* b2 = (const float*)d_in[16];
    float* out = (float*)d_out;

    char* w = (char*)d_ws;
    short* featbf = (short*)w;  w += (size_t)NN * ED * 2;
    short* xb     = (short*)w;  w += (size_t)NN * ED * 2;
    short* edgebf = (short*)w;  w += (size_t)NN * KNB * EFD * 2;
    short* timebf = (short*)w;  w += (size_t)NN * KNB * TD * 2;
    short* qb     = (short*)w;  w += (size_t)NN * DD * 2;
    short* kkb    = (short*)w;  w += (size_t)NN * DD * 2;
    short* vvT    = (short*)w;  w += (size_t)DD * NN * 2;
    short* WkT    = (short*)w;  w += (size_t)DD * KDD * 2;
    short* WvT    = (short*)w;  w += (size_t)DD * KDD * 2;
    short* WqT    = (short*)w;  w += (size_t)DD * ED * 2;
    short* WcatT  = (short*)w;  w += (size_t)ED * 320 * 2;
    short* W2T    = (short*)w;  w += (size_t)ED * ED * 2;
    float* bfold  = (float*)w;  w += (size_t)ED * 4;
    // scratch region: (psumK|psumV bf16) then reused as (opart bf16|ml fp32)
    short* psumK = (short*)w;
    short* psumV = psumK + (size_t)NSPLIT * NN * DD;
    short* opart = (short*)w;
    float* ml    = (float*)(opart + (size_t)NSPLIT * NN * DD);

    prep_convert<<<6591, 256, 0, stream>>>(
        Wk, Wv, Wq, Wo, bo, W1, b1, W2,
        features, edge_feats, time_feats, node_idx,
        WkT, WvT, WqT, WcatT, W2T, bfold, featbf, xb, edgebf, timebf);
    kvq_gemm_mfma<<<384 + 192, 256, 0, stream>>>(
        featbf, edgebf, timebf, neighbors, WkT, WvT, psumK, psumV, xb, WqT, bq, qb);
    kv_combine<<<2 * NN * DD / 4 / 256, 256, 0, stream>>>(psumK, psumV, bk, bv, kkb, vvT);
    attn_mfma<<<dim3(NN / 128, NH, NSPLIT), 512, 0, stream>>>(qb, kkb, vvT, opart, ml);
    mlp_fused<<<NN / 16, 256, 0, stream>>>(xb, opart, ml, WcatT, bfold, W2T, b2, out);
}